// Round 8
// baseline (998.050 us; speedup 1.0000x reference)
//
#include <hip/hip_runtime.h>
#include <hip/hip_bf16.h>
#include <stdint.h>

// B, L, V, D, NCTX, DEPTH, VD = (4096, 77, 49408, 512, 4, 9, 768)
#define BB   4096
#define LL   77
#define VV   49408
#define DD   512
#define NCTX 4
#define KK   8          // DEPTH - 1
#define VD   768

// Output layout (flat f32 element offsets, concatenated in return order):
// pe (B,L,D) | pt (B,L) | ctx (4,512) | proj_ctx (4,768) | cpt (8,4,512) | vdp (8,4,768)
#define OFF_PE   0L
#define OFF_PT   161480704L   // B*L*D
#define OFF_CTX  161796096L   // + B*L
#define OFF_PROJ 161798144L   // + 2048
#define OFF_CPT  161801216L   // + 3072
#define OFF_VDP  161817600L   // + 16384

typedef float f32x4 __attribute__((ext_vector_type(4)));

#define NEMB      73          // emb-sourced positions per row (pos 0, 5..76)
#define TOKSTRIDE 128         // padded stride of tok[] per row
#define VPAD      49664       // VV padded for ws carving

// k_prep_hist block-range partition
#define DOT_BLOCKS   6912     // 27648 waves, one dot output each
#define PT_BLOCKS    1024     // 4096 waves, one text row each (pt + tok + hist)
#define CPY_BLOCKS   18       // 4608 f4: ctx (512) + cpt (4096) pass-through
#define BCAST_BLOCKS 8192     // 4096*4*128 f4: pe[:,1..4,:] = ctx broadcast

// ---------------------------------------------------------------------------
// Kernel 1: dots + pt build + token list + histogram + copies + ctx broadcast
// ---------------------------------------------------------------------------
__global__ __launch_bounds__(256) void k_prep_hist(const int* __restrict__ text,
                                                   const float* __restrict__ ctx,
                                                   const float* __restrict__ proj_w,
                                                   const float* __restrict__ proj_b,
                                                   const float* __restrict__ cpt,
                                                   const float* __restrict__ cw,
                                                   const float* __restrict__ cb,
                                                   float* __restrict__ out,
                                                   int* __restrict__ cnt,
                                                   int* __restrict__ tok) {
    int blk = blockIdx.x;
    int tid = threadIdx.x;

    if (blk < DOT_BLOCKS) {
        // ---- small dots: one wave64 per output element ----
        int gid  = blk * 256 + tid;
        int wave = gid >> 6;
        int lane = gid & 63;

        const float* a;
        const float* b;
        float bias;
        float* dst;

        if (wave < NCTX * VD) {
            int n = wave / VD;
            int o = wave - n * VD;
            a    = ctx + n * DD;
            b    = proj_w + (long)o * DD;
            bias = proj_b[o];
            dst  = out + OFF_PROJ + wave;
        } else {
            int w = wave - NCTX * VD;
            int k = w / (NCTX * VD);
            int r = w - k * (NCTX * VD);
            int n = r / VD;
            int o = r - n * VD;
            a    = cpt + (long)(k * NCTX + n) * DD;
            b    = cw + (long)(k * VD + o) * DD;
            bias = cb[k * VD + o];
            dst  = out + OFF_VDP + w;
        }

        const f32x4* a4 = (const f32x4*)a + lane * 2;
        const f32x4* b4 = (const f32x4*)b + lane * 2;
        f32x4 x0 = a4[0], x1 = a4[1];
        f32x4 y0 = b4[0], y1 = b4[1];
        float s = x0.x * y0.x + x0.y * y0.y + x0.z * y0.z + x0.w * y0.w
                + x1.x * y1.x + x1.y * y1.y + x1.z * y1.z + x1.w * y1.w;
        #pragma unroll
        for (int off = 32; off; off >>= 1) s += __shfl_xor(s, off);
        if (lane == 0) *dst = s + bias;

    } else if (blk < DOT_BLOCKS + PT_BLOCKS) {
        // ---- pt + token list + histogram: one wave64 per text row ----
        int gid  = (blk - DOT_BLOCKS) * 256 + tid;
        int row  = gid >> 6;
        int lane = gid & 63;
        const int* t = text + row * LL;

        int v0 = (lane < LL) ? t[lane] : 0;
        int v1 = (lane + 64 < LL) ? t[lane + 64] : 0;
        int m = v0 > v1 ? v0 : v1;
        #pragma unroll
        for (int off = 32; off; off >>= 1) {
            int o = __shfl_xor(m, off);
            m = o > m ? o : m;
        }
        // m == row max == eot token

        float* pt_dst = out + OFF_PT + (long)row * LL;
        int*   trow   = tok + (long)row * TOKSTRIDE;
        #pragma unroll
        for (int pass = 0; pass < 2; ++pass) {
            int pos = lane + pass * 64;
            if (pos < LL) {
                int v;
                if (pos == 0)           v = t[0];
                else if (pos <= NCTX)   v = 0;
                else if (pos == LL - 1) { int x = t[LL - 5]; v = (x != 0) ? m : 0; }
                else                    v = t[pos - NCTX];
                pt_dst[pos] = (float)v;
                if (pos == 0 || pos > NCTX) {         // emb-sourced position
                    int e = (pos == 0) ? 0 : pos - NCTX;   // [0, 73)
                    trow[e] = v;
                    atomicAdd(&cnt[v], 1);
                }
            }
        }

    } else if (blk < DOT_BLOCKS + PT_BLOCKS + CPY_BLOCKS) {
        // ---- pass-through copies: ctx (512 f4) then cpt (4096 f4) ----
        int i = (blk - DOT_BLOCKS - PT_BLOCKS) * 256 + tid;   // [0, 4608)
        const f32x4* c4 = (const f32x4*)ctx;
        const f32x4* p4 = (const f32x4*)cpt;
        f32x4* o4 = (f32x4*)out;
        if (i < 512) {
            o4[OFF_CTX / 4 + i] = c4[i];
        } else {
            o4[OFF_CPT / 4 + (i - 512)] = p4[i - 512];
        }

    } else {
        // ---- ctx broadcast into pe[:, 1..4, :]: 4096*4*128 f4 ----
        int g = (blk - DOT_BLOCKS - PT_BLOCKS - CPY_BLOCKS) * 256 + tid;
        int b = g >> 9;            // 512 f4 per batch row (4 pos * 128)
        int j = (g >> 7) & 3;      // ctx row
        int c = g & 127;
        const f32x4* c4 = (const f32x4*)ctx;
        f32x4* pe4 = (f32x4*)out;  // OFF_PE == 0
        __builtin_nontemporal_store(c4[j * 128 + c],
                                    pe4 + ((long)b * LL + 1 + j) * 128 + c);
    }
}

// ---------------------------------------------------------------------------
// Kernel 2: exclusive prefix sum over cnt[VV] -> off[], cur[] (single block)
// ---------------------------------------------------------------------------
#define SCAN_T 1024
#define CHUNK  49            // 1024*49 = 50176 >= VV
__global__ __launch_bounds__(SCAN_T) void k_scan(const int* __restrict__ cnt,
                                                 int* __restrict__ off,
                                                 int* __restrict__ cur) {
    __shared__ int sdata[SCAN_T];
    int tid  = threadIdx.x;
    int base = tid * CHUNK;

    int lsum = 0;
    #pragma unroll 4
    for (int k = 0; k < CHUNK; ++k) {
        int i = base + k;
        if (i < VV) lsum += cnt[i];
    }
    sdata[tid] = lsum;
    __syncthreads();
    // inclusive scan over 1024 partials (Hillis-Steele, double barrier)
    for (int d = 1; d < SCAN_T; d <<= 1) {
        int v = (tid >= d) ? sdata[tid - d] : 0;
        __syncthreads();
        sdata[tid] += v;
        __syncthreads();
    }
    int run = sdata[tid] - lsum;    // exclusive start of this thread's chunk
    #pragma unroll 4
    for (int k = 0; k < CHUNK; ++k) {
        int i = base + k;
        if (i < VV) {
            off[i] = run;
            cur[i] = run;
            run += cnt[i];
        }
    }
}

// ---------------------------------------------------------------------------
// Kernel 3: scatter (row,pos) refs into token-sorted pairs[]
// ---------------------------------------------------------------------------
__global__ __launch_bounds__(256) void k_scatter(const int* __restrict__ tok,
                                                 int* __restrict__ cur,
                                                 int* __restrict__ pairs) {
    int g = blockIdx.x * 256 + threadIdx.x;   // [0, BB*128)
    int r = g >> 7;
    int e = g & 127;
    if (e < NEMB) {
        int v   = tok[(long)r * TOKSTRIDE + e];
        int pos = (e == 0) ? 0 : e + NCTX;
        int idx = atomicAdd(&cur[v], 1);
        pairs[idx] = r * LL + pos;
    }
}

// ---------------------------------------------------------------------------
// Kernel 4: dedup multicast gather. One wave per token: read 2 KB emb row
// once, NT-store to all destinations.
// ---------------------------------------------------------------------------
__global__ __launch_bounds__(256) void k_gather_dedup(const f32x4* __restrict__ emb,
                                                      const int* __restrict__ off,
                                                      const int* __restrict__ cnt,
                                                      const int* __restrict__ pairs,
                                                      f32x4* __restrict__ pe) {
    int gid  = blockIdx.x * 256 + threadIdx.x;
    int t    = gid >> 6;          // token id == wave id, [0, VV)
    int lane = gid & 63;

    int n = cnt[t];
    if (n == 0) return;
    int o = off[t];

    const f32x4* er = emb + (long)t * 128 + lane * 2;
    f32x4 r0 = er[0];
    f32x4 r1 = er[1];

    for (int base = 0; base < n; base += 64) {
        int mcnt = n - base; if (mcnt > 64) mcnt = 64;
        int flat = (lane < mcnt) ? pairs[o + base + lane] : 0;
        for (int j = 0; j < mcnt; ++j) {
            int f = __shfl(flat, j);
            f32x4* d = pe + (long)f * 128 + lane * 2;
            __builtin_nontemporal_store(r0, d);
            __builtin_nontemporal_store(r1, d + 1);
        }
    }
}

extern "C" void kernel_launch(void* const* d_in, const int* in_sizes, int n_in,
                              void* d_out, int out_size, void* d_ws, size_t ws_size,
                              hipStream_t stream) {
    const int*   text   = (const int*)d_in[0];
    const float* emb    = (const float*)d_in[1];
    const float* ctx    = (const float*)d_in[2];
    const float* proj_w = (const float*)d_in[3];
    const float* proj_b = (const float*)d_in[4];
    const float* cpt    = (const float*)d_in[5];
    const float* cw     = (const float*)d_in[6];
    const float* cb     = (const float*)d_in[7];
    float* out = (float*)d_out;

    // workspace carve (ints): cnt | off | cur | tok | pairs  (~4 MB total)
    int* cnt   = (int*)d_ws;
    int* off   = cnt + VPAD;
    int* cur   = off + VPAD;
    int* tok   = cur + VPAD;
    int* pairs = tok + (long)BB * TOKSTRIDE;

    // 0) zero the histogram (async memset is graph-capture safe)
    hipMemsetAsync(cnt, 0, VV * sizeof(int), stream);

    // 1) dots + pt + tok + hist + copies + ctx broadcast
    k_prep_hist<<<DOT_BLOCKS + PT_BLOCKS + CPY_BLOCKS + BCAST_BLOCKS, 256, 0,
                  stream>>>(text, ctx, proj_w, proj_b, cpt, cw, cb, out, cnt, tok);

    // 2) prefix sum -> off, cur
    k_scan<<<1, SCAN_T, 0, stream>>>(cnt, off, cur);

    // 3) scatter refs token-sorted
    k_scatter<<<BB * 128 / 256, 256, 0, stream>>>(tok, cur, pairs);

    // 4) dedup multicast gather (one wave per token)
    k_gather_dedup<<<VV * 64 / 256, 256, 0, stream>>>((const f32x4*)emb,
                                                      off, cnt, pairs,
                                                      (f32x4*)(out + OFF_PE));
}

// Round 9
// 764.057 us; speedup vs baseline: 1.3063x; 1.3063x over previous
//
#include <hip/hip_runtime.h>
#include <hip/hip_bf16.h>
#include <stdint.h>

// B, L, V, D, NCTX, DEPTH, VD = (4096, 77, 49408, 512, 4, 9, 768)
#define BB   4096
#define LL   77
#define DD   512
#define NCTX 4
#define KK   8          // DEPTH - 1
#define VD   768

// Output layout (flat f32 element offsets, concatenated in return order):
// pe (B,L,D) | pt (B,L) | ctx (4,512) | proj_ctx (4,768) | cpt (8,4,512) | vdp (8,4,768)
#define OFF_PE   0L
#define OFF_PT   161480704L   // B*L*D
#define OFF_CTX  161796096L   // + B*L
#define OFF_PROJ 161798144L   // + 2048
#define OFF_CPT  161801216L   // + 3072
#define OFF_VDP  161817600L   // + 16384

typedef float f32x4 __attribute__((ext_vector_type(4)));

// Block-range partition: [0,BB) row-gather | [BB, BB+DOT_BLOCKS) dots | copies
#define DOT_BLOCKS 6912       // 27648 waves, one output elem each
#define CPY_BLOCKS 18         // 4608 float4 (ctx 512 + cpt 4096)
#define ROW_F4     (LL * DD / 4)   // 9856 float4 per text row

__global__ __launch_bounds__(256) void k_main(const int* __restrict__ text,
                                              const float* __restrict__ emb,
                                              const float* __restrict__ ctx,
                                              const float* __restrict__ proj_w,
                                              const float* __restrict__ proj_b,
                                              const float* __restrict__ cpt,
                                              const float* __restrict__ cw,
                                              const float* __restrict__ cb,
                                              float* __restrict__ out) {
    int blk = blockIdx.x;
    int tid = threadIdx.x;

    if (blk < BB) {
        // ================= row gather: one block per text row =================
        __shared__ uintptr_t srcp[LL];   // per-position source row pointer
        __shared__ int smax;
        const int* t = text + blk * LL;

        // wave 0: row max (= eot token, since eot = text[argmax] = max)
        if (tid < 64) {
            int v0 = (tid < LL) ? t[tid] : 0;
            int v1 = (tid + 64 < LL) ? t[tid + 64] : 0;
            int m = v0 > v1 ? v0 : v1;
            #pragma unroll
            for (int off = 32; off; off >>= 1) {
                int o = __shfl_xor(m, off);
                m = o > m ? o : m;
            }
            if (tid == 0) smax = m;
        }
        __syncthreads();

        // threads 0..76: token + source pointer per position; write pt (f32)
        if (tid < LL) {
            int v;
            if (tid == 0)           v = t[0];
            else if (tid <= NCTX)   v = 0;
            else if (tid == LL - 1) { int x = t[LL - 5]; v = (x != 0) ? smax : 0; }
            else                    v = t[tid - NCTX];

            const float* s;
            if (tid >= 1 && tid <= NCTX) s = ctx + (tid - 1) * DD;
            else                         s = emb + (long)v * DD;
            srcp[tid] = (uintptr_t)s;
            out[OFF_PT + (long)blk * LL + tid] = (float)v;
        }
        __syncthreads();

        // stream the 77*512-float slab, phase-split:
        // 8 independent loads into regs (read burst), then 8 NT stores
        // (write burst). 5 phases cover 9856 f4.
        f32x4* dst = (f32x4*)out + (long)blk * ROW_F4;   // OFF_PE == 0
        for (int base = 0; base < ROW_F4; base += 8 * 256) {
            f32x4 v[8];
            #pragma unroll
            for (int k = 0; k < 8; ++k) {
                int i = base + k * 256 + tid;
                if (i < ROW_F4) {
                    int p = i >> 7;          // position (128 f4 per position)
                    int c = i & 127;
                    v[k] = ((const f32x4*)srcp[p])[c];
                }
            }
            #pragma unroll
            for (int k = 0; k < 8; ++k) {
                int i = base + k * 256 + tid;
                if (i < ROW_F4) __builtin_nontemporal_store(v[k], dst + i);
            }
        }

    } else if (blk < BB + DOT_BLOCKS) {
        // ================= small dots: one wave64 per output element ==========
        int gid  = (blk - BB) * 256 + tid;
        int wave = gid >> 6;
        int lane = gid & 63;

        const float* a;
        const float* b;
        float bias;
        float* dst;

        if (wave < NCTX * VD) {
            int n = wave / VD;
            int o = wave - n * VD;
            a    = ctx + n * DD;
            b    = proj_w + (long)o * DD;
            bias = proj_b[o];
            dst  = out + OFF_PROJ + wave;
        } else {
            int w = wave - NCTX * VD;
            int k = w / (NCTX * VD);
            int r = w - k * (NCTX * VD);
            int n = r / VD;
            int o = r - n * VD;
            a    = cpt + (long)(k * NCTX + n) * DD;
            b    = cw + (long)(k * VD + o) * DD;
            bias = cb[k * VD + o];
            dst  = out + OFF_VDP + w;
        }

        const f32x4* a4 = (const f32x4*)a + lane * 2;
        const f32x4* b4 = (const f32x4*)b + lane * 2;
        f32x4 x0 = a4[0], x1 = a4[1];
        f32x4 y0 = b4[0], y1 = b4[1];
        float s = x0.x * y0.x + x0.y * y0.y + x0.z * y0.z + x0.w * y0.w
                + x1.x * y1.x + x1.y * y1.y + x1.z * y1.z + x1.w * y1.w;
        #pragma unroll
        for (int off = 32; off; off >>= 1) s += __shfl_xor(s, off);
        if (lane == 0) *dst = s + bias;

    } else {
        // ================= pass-through copies ===============================
        int i = (blk - BB - DOT_BLOCKS) * 256 + tid;   // [0, 4608)
        const f32x4* c4 = (const f32x4*)ctx;
        const f32x4* p4 = (const f32x4*)cpt;
        f32x4* o4 = (f32x4*)out;
        if (i < 512) {
            o4[OFF_CTX / 4 + i] = c4[i];
        } else {
            o4[OFF_CPT / 4 + (i - 512)] = p4[i - 512];
        }
    }
}

extern "C" void kernel_launch(void* const* d_in, const int* in_sizes, int n_in,
                              void* d_out, int out_size, void* d_ws, size_t ws_size,
                              hipStream_t stream) {
    const int*   text   = (const int*)d_in[0];
    const float* emb    = (const float*)d_in[1];
    const float* ctx    = (const float*)d_in[2];
    const float* proj_w = (const float*)d_in[3];
    const float* proj_b = (const float*)d_in[4];
    const float* cpt    = (const float*)d_in[5];
    const float* cw     = (const float*)d_in[6];
    const float* cb     = (const float*)d_in[7];
    float* out = (float*)d_out;

    k_main<<<BB + DOT_BLOCKS + CPY_BLOCKS, 256, 0, stream>>>(
        text, emb, ctx, proj_w, proj_b, cpt, cw, cb, out);
}